// Round 18
// baseline (161.023 us; speedup 1.0000x reference)
//
#include <hip/hip_runtime.h>

// MHSA fwd MFMA bf16: B=8, N=1024, D=1024, H=16, DK=64. fp32 in/out, bf16 compute.
// Round 18: attention v8 — P_lds eliminated via in-register P redistribution
// (shfl_xor 32/16 + parity selects); 3-buf K/V (48KB, 3 blocks/CU held) with
// counted vmcnt(2) + raw barriers (deep pipeline, no prefetch drain).
// GEMM1 = R17 128x384 BK=32 relaxed; GEMM2 = R14 128x256 BK=64 relaxed.

typedef __attribute__((ext_vector_type(8))) short bf16x8;
typedef __attribute__((ext_vector_type(4))) float f32x4;

#define GLOAD_LDS16(gp, lp)                                                              \
  __builtin_amdgcn_global_load_lds((const __attribute__((address_space(1))) void*)(gp),  \
                                   (__attribute__((address_space(3))) void*)(lp), 16, 0, 0)

__device__ __forceinline__ unsigned short f2bf(float f) {
  unsigned int u = __float_as_uint(f);
  u += 0x7fffu + ((u >> 16) & 1u);          // RNE
  return (unsigned short)(u >> 16);
}

// ---------------------------------------------------------------------------
// Fused pre-pass: blocks [0,2048) cast x->bf16; [2048,5120) transpose W_qkv;
// [5120,6144) transpose W_o.
// ---------------------------------------------------------------------------
__global__ __launch_bounds__(256) void prep_fused(
    const float* __restrict__ x, unsigned short* __restrict__ x_bf,
    const float* __restrict__ W_qkv, unsigned short* __restrict__ wqkv_t,
    const float* __restrict__ W_o, unsigned short* __restrict__ wo_t) {
  const int b = blockIdx.x;
  if (b < 2048) {
    const int n4 = 8388608 / 4;
    for (int i = b * 256 + threadIdx.x; i < n4; i += 2048 * 256) {
      float4 v = reinterpret_cast<const float4*>(x)[i];
      ushort4 o;
      o.x = f2bf(v.x); o.y = f2bf(v.y); o.z = f2bf(v.z); o.w = f2bf(v.w);
      reinterpret_cast<ushort4*>(x_bf)[i] = o;
    }
  } else {
    __shared__ float tile[32][33];
    const float* W;
    unsigned short* Wt;
    int R = 1024, C, bx, by;
    if (b < 5120) {
      W = W_qkv; Wt = wqkv_t; C = 3072;
      int bb = b - 2048; bx = bb % 96; by = bb / 96;
    } else {
      W = W_o; Wt = wo_t; C = 1024;
      int bb = b - 5120; bx = bb & 31; by = bb >> 5;
    }
    const int tx = threadIdx.x & 31, ty = threadIdx.x >> 5;
    const int c0 = bx * 32, r0 = by * 32;
    #pragma unroll
    for (int i = 0; i < 4; i++) {
      int r = r0 + ty + i * 8;
      tile[ty + i * 8][tx] = W[(size_t)r * C + c0 + tx];
    }
    __syncthreads();
    #pragma unroll
    for (int i = 0; i < 4; i++) {
      int c = c0 + ty + i * 8;
      Wt[(size_t)c * R + r0 + tx] = f2bf(tile[tx][ty + i * 8]);
    }
  }
}

// ---------------------------------------------------------------------------
// GEMM1 (R17): 128x384, BK=32, 512 thr (8 waves = 2M x 4N; 64x96 per wave).
// 3-buf LDS (96 KB), stage kt+2 during kt, ONE tile-top vmcnt(4)+barrier+
// sched_barrier per tile. qkv scatter epilogue with per-frag `which`.
// ---------------------------------------------------------------------------
__global__ __launch_bounds__(512) void gemm1_384(
    const unsigned short* __restrict__ A, const unsigned short* __restrict__ Bt,
    const float* __restrict__ bias, unsigned short* __restrict__ qkv_out) {
  __shared__ __align__(16) unsigned short As[3][128 * 32];   // 24 KB
  __shared__ __align__(16) unsigned short Bs[3][384 * 32];   // 72 KB
  const int t = threadIdx.x;
  const int lane = t & 63, wid = t >> 6;
  const int lr = lane & 15, g = lane >> 4;
  const int wm = wid >> 2, wn = wid & 3;

  const int nwg = gridDim.x * gridDim.y;
  const int id = blockIdx.x + gridDim.x * blockIdx.y;
  const int sw = (id & 7) * (nwg >> 3) + (id >> 3);
  const int bx = sw % gridDim.x, by = sw / gridDim.x;
  const int row0 = by * 128, col0 = bx * 384;

  const int srow = t >> 2;                       // 0..127 (64B rows: 32 bf16)
  const int sch  = (t & 3) ^ ((srow >> 1) & 3);  // source pre-swizzle chunk

  auto stA = [&](int buf, int kt) {
    GLOAD_LDS16(A + (size_t)(row0 + srow) * 1024 + kt * 32 + sch * 8,
                (char*)&As[buf][0] + t * 16);
  };
  auto stB = [&](int buf, int kt, int j) {
    GLOAD_LDS16(Bt + (size_t)(col0 + j * 128 + srow) * 1024 + kt * 32 + sch * 8,
                (char*)&Bs[buf][0] + j * 8192 + t * 16);
  };
  auto rdA = [&](int buf, int m) -> bf16x8 {
    int r = wm * 64 + m * 16 + lr;
    return *(const bf16x8*)((const char*)&As[buf][0] + r * 64 +
                            ((g ^ ((r >> 1) & 3)) * 16));
  };
  auto rdB = [&](int buf, int n) -> bf16x8 {
    int r = wn * 96 + n * 16 + lr;
    return *(const bf16x8*)((const char*)&Bs[buf][0] + r * 64 +
                            ((g ^ ((r >> 1) & 3)) * 16));
  };

  f32x4 acc[4][6] = {};

  stA(0, 0); stB(0, 0, 0); stB(0, 0, 1); stB(0, 0, 2);
  stA(1, 1); stB(1, 1, 0); stB(1, 1, 1); stB(1, 1, 2);

  for (int kt = 0; kt < 32; kt++) {
    const int buf = kt % 3;
    const int bufn = (kt + 2) % 3;
    const bool pf = (kt <= 29);

    if (kt == 31) asm volatile("s_waitcnt vmcnt(0)" ::: "memory");
    else          asm volatile("s_waitcnt vmcnt(4)" ::: "memory");
    __builtin_amdgcn_s_barrier();
    __builtin_amdgcn_sched_barrier(0);

    bf16x8 a[4], b[6];
    #pragma unroll
    for (int m = 0; m < 4; m++) a[m] = rdA(buf, m);
    #pragma unroll
    for (int n = 0; n < 6; n++) b[n] = rdB(buf, n);
    if (pf) { stA(bufn, kt + 2); stB(bufn, kt + 2, 0); stB(bufn, kt + 2, 1); stB(bufn, kt + 2, 2); }
    #pragma unroll
    for (int m = 0; m < 4; m++)
      #pragma unroll
      for (int n = 0; n < 6; n++)
        acc[m][n] = __builtin_amdgcn_mfma_f32_16x16x32_bf16(a[m], b[n], acc[m][n], 0, 0, 0);
  }

  #pragma unroll
  for (int m = 0; m < 4; m++) {
    const int row = row0 + wm * 64 + m * 16 + g * 4;
    const int bb = row >> 10, nn = row & 1023;
    #pragma unroll
    for (int n = 0; n < 6; n++) {
      const int col = col0 + wn * 96 + n * 16 + lr;
      const int which = col >> 10;
      const int cc = col & 1023;
      const int h = cc >> 6, dk = cc & 63;
      const float bv = bias[col];
      if (which == 2) {
        ushort4 w;
        w.x = f2bf(acc[m][n][0] + bv);
        w.y = f2bf(acc[m][n][1] + bv);
        w.z = f2bf(acc[m][n][2] + bv);
        w.w = f2bf(acc[m][n][3] + bv);
        size_t idx = ((size_t)2 << 23) + (((size_t)(bb * 16 + h)) << 16) +
                     (size_t)dk * 1024 + nn;
        *(ushort4*)(qkv_out + idx) = w;
      } else {
        const float sc = (which == 0) ? 0.125f : 1.0f;
        #pragma unroll
        for (int r = 0; r < 4; r++) {
          size_t idx = ((size_t)which << 23) +
                       (((size_t)((bb * 16 + h) * 1024 + nn + r)) << 6) + dk;
          qkv_out[idx] = f2bf((acc[m][n][r] + bv) * sc);
        }
      }
    }
  }
}

// ---------------------------------------------------------------------------
// GEMM2 (R14 relaxed): 128x256, BK=64, 8 waves (2M x 4N, 64x64/wave), 3-buf,
// stage kt+2, tile-top vmcnt(6)+barrier+sched_barrier. f32 out + bias.
// ---------------------------------------------------------------------------
__global__ __launch_bounds__(512) void gemm2_k(
    const unsigned short* __restrict__ A, const unsigned short* __restrict__ Bt,
    const float* __restrict__ bias, float* __restrict__ Cout) {
  __shared__ __align__(16) unsigned short As[3][128 * 64];   // 48 KB
  __shared__ __align__(16) unsigned short Bs[3][256 * 64];   // 96 KB
  const int t = threadIdx.x;
  const int lane = t & 63, wid = t >> 6;
  const int lr = lane & 15, g = lane >> 4;
  const int wm = wid >> 2, wn = wid & 3;

  const int nwg = gridDim.x * gridDim.y;
  const int id = blockIdx.x + gridDim.x * blockIdx.y;
  const int sw = (id & 7) * (nwg >> 3) + (id >> 3);
  const int bx = sw % gridDim.x, by = sw / gridDim.x;
  const int row0 = by * 128, col0 = bx * 256;

  const int srow = t >> 3, sch = t & 7;

  auto stA = [&](int buf, int kt, int j) {
    int row = j * 64 + srow;
    int ch = sch ^ (row & 7);
    GLOAD_LDS16(A + (size_t)(row0 + row) * 1024 + kt * 64 + ch * 8,
                (char*)&As[buf][0] + j * 8192 + t * 16);
  };
  auto stB = [&](int buf, int kt, int j) {
    int row = j * 64 + srow;
    int ch = sch ^ (row & 7);
    GLOAD_LDS16(Bt + (size_t)(col0 + row) * 1024 + kt * 64 + ch * 8,
                (char*)&Bs[buf][0] + j * 8192 + t * 16);
  };
  auto rdA = [&](int buf, int c, int m) -> bf16x8 {
    int r = wm * 64 + m * 16 + lr;
    return *(const bf16x8*)((const char*)&As[buf][0] + r * 128 +
                            ((c * 64 + g * 16) ^ ((r & 7) << 4)));
  };
  auto rdB = [&](int buf, int c, int n) -> bf16x8 {
    int r = wn * 64 + n * 16 + lr;
    return *(const bf16x8*)((const char*)&Bs[buf][0] + r * 128 +
                            ((c * 64 + g * 16) ^ ((r & 7) << 4)));
  };

  f32x4 acc[4][4] = {};

  stA(0, 0, 0); stA(0, 0, 1);
  stB(0, 0, 0); stB(0, 0, 1); stB(0, 0, 2); stB(0, 0, 3);
  stA(1, 1, 0); stA(1, 1, 1);
  stB(1, 1, 0); stB(1, 1, 1); stB(1, 1, 2); stB(1, 1, 3);

  for (int kt = 0; kt < 16; kt++) {
    const int buf = kt % 3;
    const int bufn = (kt + 2) % 3;
    const bool pf = (kt <= 13);

    if (kt == 15) asm volatile("s_waitcnt vmcnt(0)" ::: "memory");
    else          asm volatile("s_waitcnt vmcnt(6)" ::: "memory");
    __builtin_amdgcn_s_barrier();
    __builtin_amdgcn_sched_barrier(0);

    bf16x8 a0[4], b0[4];
    #pragma unroll
    for (int m = 0; m < 4; m++) a0[m] = rdA(buf, 0, m);
    #pragma unroll
    for (int n = 0; n < 4; n++) b0[n] = rdB(buf, 0, n);
    if (pf) { stA(bufn, kt + 2, 0); stA(bufn, kt + 2, 1); stB(bufn, kt + 2, 0); }
    #pragma unroll
    for (int m = 0; m < 4; m++)
      #pragma unroll
      for (int n = 0; n < 4; n++)
        acc[m][n] = __builtin_amdgcn_mfma_f32_16x16x32_bf16(a0[m], b0[n], acc[m][n], 0, 0, 0);

    bf16x8 a1[4], b1[4];
    #pragma unroll
    for (int m = 0; m < 4; m++) a1[m] = rdA(buf, 1, m);
    #pragma unroll
    for (int n = 0; n < 4; n++) b1[n] = rdB(buf, 1, n);
    if (pf) { stB(bufn, kt + 2, 1); stB(bufn, kt + 2, 2); stB(bufn, kt + 2, 3); }
    #pragma unroll
    for (int m = 0; m < 4; m++)
      #pragma unroll
      for (int n = 0; n < 4; n++)
        acc[m][n] = __builtin_amdgcn_mfma_f32_16x16x32_bf16(a1[m], b1[n], acc[m][n], 0, 0, 0);
  }

  #pragma unroll
  for (int m = 0; m < 4; m++) {
    #pragma unroll
    for (int n = 0; n < 4; n++) {
      int col = col0 + wn * 64 + n * 16 + lr;
      #pragma unroll
      for (int r = 0; r < 4; r++) {
        int row = row0 + wm * 64 + m * 16 + g * 4 + r;
        Cout[(size_t)row * 1024 + col] = acc[m][n][r] + bias[col];
      }
    }
  }
}

// ---------------------------------------------------------------------------
// Attention v8: 8 waves, QBLK=128, KVBLK=64. 3-buf K/V (48 KB), stage(kt+2)
// at tile top, end-of-tile vmcnt(2) + raw barrier (deep pipeline). Swapped
// QK^T; P redistributed IN-REGISTER to the PV A-fragment layout:
//   source: lane(lr,g) holds P[q=lr][k=16ks+4g+r] packed as wv[ks][i]
//   target: pa[c] words wi = P[q=lr][k=32c+8g+2wi,+1]
//   mapping: j=2c+(wi&1): r0=[A_lo|B_lo], r1=[A_hi|B_hi] (A=wv[even ks],
//   B=wv[odd ks] via lane-32 half-exchange), then xor-16 + g-parity select.
// No P_lds, no den array (scalar den_l, reduced at end).
// ---------------------------------------------------------------------------
__global__ __launch_bounds__(512, 6) void attn_mfma(
    const unsigned short* __restrict__ qkv, unsigned short* __restrict__ attn_out) {
  __shared__ __align__(16) unsigned short K_lds[3][64 * 64];   // [k][d] swz, 24 KB
  __shared__ __align__(16) unsigned short V_lds[3][64 * 64];   // [d][k] swz, 24 KB

  const int bid = ((blockIdx.x & 7) << 7) + (blockIdx.x >> 3);
  const int bh = bid >> 3, qt = bid & 7;
  const unsigned short* Qp = qkv + ((size_t)bh << 16);
  const unsigned short* Kp = qkv + (1u << 23) + ((size_t)bh << 16);
  const unsigned short* Vt = qkv + (2u << 23) + ((size_t)bh << 16);  // [dk][n]

  const int t = threadIdx.x;
  const int lane = t & 63, wid = t >> 6;
  const int lr = lane & 15, g = lane >> 4;

  bf16x8 qf[2];
  {
    int qrow = qt * 128 + wid * 16 + lr;
    qf[0] = *(const bf16x8*)(Qp + (size_t)qrow * 64 + g * 8);
    qf[1] = *(const bf16x8*)(Qp + (size_t)qrow * 64 + 32 + g * 8);
  }

  const int srow = t >> 3;
  const int sch  = (t & 7) ^ (srow & 7);
  const int so   = t * 16;

  auto stage = [&](int buf, int kt) {
    GLOAD_LDS16(Kp + (size_t)(kt * 64 + srow) * 64 + sch * 8, (char*)&K_lds[buf][0] + so);
    GLOAD_LDS16(Vt + (size_t)srow * 1024 + kt * 64 + sch * 8, (char*)&V_lds[buf][0] + so);
  };

  f32x4 o_acc[4] = {};
  float den_l = 0.f;
  const bool lo_half = (lane < 32);
  const bool godd = (g & 1) != 0;

  // prologue: 2 tiles in flight, wait only for tile 0
  stage(0, 0); stage(1, 1);
  asm volatile("s_waitcnt vmcnt(2)" ::: "memory");
  __builtin_amdgcn_s_barrier();

  for (int kt = 0; kt < 16; kt++) {
    const int buf = kt % 3;
    if (kt + 2 < 16) stage((kt + 2) % 3, kt + 2);

    // swapped QK^T: lane holds P[q=lr][k=16ks+4g+r]
    f32x4 s4[4] = {};
    __builtin_amdgcn_s_setprio(1);
    #pragma unroll
    for (int ks = 0; ks < 4; ks++) {
      int krow = ks * 16 + lr;
      #pragma unroll
      for (int c = 0; c < 2; c++) {
        bf16x8 kf = *(const bf16x8*)((char*)&K_lds[buf][0] + krow * 128 +
                                     ((c * 64 + g * 16) ^ ((krow & 7) << 4)));
        s4[ks] = __builtin_amdgcn_mfma_f32_16x16x32_bf16(kf, qf[c], s4[ks], 0, 0, 0);
      }
    }
    __builtin_amdgcn_s_setprio(0);

    // exp + pack to u32 pairs
    unsigned int wv[4][2];
    #pragma unroll
    for (int ks = 0; ks < 4; ks++) {
      float e0 = __expf(s4[ks][0]);
      float e1 = __expf(s4[ks][1]);
      float e2 = __expf(s4[ks][2]);
      float e3 = __expf(s4[ks][3]);
      den_l += (e0 + e1) + (e2 + e3);
      wv[ks][0] = (unsigned int)f2bf(e0) | ((unsigned int)f2bf(e1) << 16);
      wv[ks][1] = (unsigned int)f2bf(e2) | ((unsigned int)f2bf(e3) << 16);
    }

    // in-register redistribution to PV A-fragment layout
    unsigned int paw[2][4];
    #pragma unroll
    for (int j = 0; j < 4; j++) {
      unsigned int a = wv[(j >> 1) * 2][j & 1];       // A_j (even ks)
      unsigned int b = wv[(j >> 1) * 2 + 1][j & 1];   // B_j (odd ks)
      unsigned int ax = (unsigned int)__shfl_xor((int)a, 32, 64);
      unsigned int bx = (unsigned int)__shfl_xor((int)b, 32, 64);
      unsigned int r0 = lo_half ? a : bx;             // [A_lo | B_lo]
      unsigned int r1 = lo_half ? ax : b;             // [A_hi | B_hi]
      unsigned int s0 = (unsigned int)__shfl_xor((int)r0, 16, 64);
      unsigned int s1 = (unsigned int)__shfl_xor((int)r1, 16, 64);
      const int c = j >> 1, i = j & 1;
      paw[c][i]     = godd ? s1 : r0;   // words 0,1
      paw[c][2 + i] = godd ? r1 : s0;   // words 2,3
    }
    bf16x8 pa[2];
    #pragma unroll
    for (int c = 0; c < 2; c++) {
      union { bf16x8 v; unsigned int u[4]; } cv;
      cv.u[0] = paw[c][0]; cv.u[1] = paw[c][1];
      cv.u[2] = paw[c][2]; cv.u[3] = paw[c][3];
      pa[c] = cv.v;
    }

    __builtin_amdgcn_s_setprio(1);
    #pragma unroll
    for (int ds_ = 0; ds_ < 4; ds_++) {
      int drow = ds_ * 16 + lr;
      #pragma unroll
      for (int c = 0; c < 2; c++) {
        bf16x8 vf = *(const bf16x8*)((char*)&V_lds[buf][0] + drow * 128 +
                                     ((c * 64 + g * 16) ^ ((drow & 7) << 4)));
        o_acc[ds_] = __builtin_amdgcn_mfma_f32_16x16x32_bf16(pa[c], vf, o_acc[ds_], 0, 0, 0);
      }
    }
    __builtin_amdgcn_s_setprio(0);

    // end of tile: kt+1 landed (kt+2 stays in flight); no full drain mid-loop
    if (kt <= 13)      asm volatile("s_waitcnt vmcnt(2)" ::: "memory");
    else if (kt == 14) asm volatile("s_waitcnt vmcnt(0)" ::: "memory");
    if (kt < 15) {
      __builtin_amdgcn_s_barrier();
      __builtin_amdgcn_sched_barrier(0);
    }
  }

  // den: reduce across g-groups; lane l then holds den(q=l&15)
  den_l += __shfl_xor(den_l, 16, 64);
  den_l += __shfl_xor(den_l, 32, 64);
  float den_r[4];
  #pragma unroll
  for (int r = 0; r < 4; r++) den_r[r] = __shfl(den_l, g * 4 + r, 64);

  const int bb = bh >> 4, h = bh & 15;
  #pragma unroll
  for (int ds_ = 0; ds_ < 4; ds_++) {
    #pragma unroll
    for (int r = 0; r < 4; r++) {
      int q = qt * 128 + wid * 16 + g * 4 + r;
      int d = h * 64 + ds_ * 16 + lr;
      attn_out[((size_t)(bb * 1024 + q)) * 1024 + d] = f2bf(o_acc[ds_][r] / den_r[r]);
    }
  }
}

// ---------------------------------------------------------------------------
extern "C" void kernel_launch(void* const* d_in, const int* in_sizes, int n_in,
                              void* d_out, int out_size, void* d_ws, size_t ws_size,
                              hipStream_t stream) {
  const float* x     = (const float*)d_in[0];
  const float* W_qkv = (const float*)d_in[1];
  const float* b_qkv = (const float*)d_in[2];
  const float* W_o   = (const float*)d_in[3];
  const float* b_o   = (const float*)d_in[4];
  float* out = (float*)d_out;

  unsigned short* ws      = (unsigned short*)d_ws;
  unsigned short* x_bf    = ws;                     //  8388608
  unsigned short* wqkv_t  = x_bf + 8388608;         //  3145728
  unsigned short* wo_t    = wqkv_t + 3145728;       //  1048576
  unsigned short* qkv     = wo_t + 1048576;         // 25165824 (3 x 2^23)
  unsigned short* attn_o  = qkv + 25165824;         //  8388608

  prep_fused<<<6144, 256, 0, stream>>>(x, x_bf, W_qkv, wqkv_t, W_o, wo_t);
  gemm1_384<<<dim3(8, 64), 512, 0, stream>>>(x_bf, wqkv_t, b_qkv, qkv);
  attn_mfma<<<1024, 512, 0, stream>>>(qkv, attn_o);
  gemm2_k<<<dim3(4, 64), 512, 0, stream>>>(attn_o, wo_t, b_o, out);
}

// Round 19
// 152.982 us; speedup vs baseline: 1.0526x; 1.0526x over previous
//
#include <hip/hip_runtime.h>

// MHSA fwd MFMA bf16: B=8, N=1024, D=1024, H=16, DK=64. fp32 in/out, bf16 compute.
// Round 19 (final composition = R17, measured 153.4us):
//   prep_fused: cast x->bf16 + transpose W_qkv/W_o (one dispatch)
//   gemm1_384: 128x384 BK=32, relaxed 1-barrier/tile, depth-2 counted vmcnt(4)
//   attn_mfma: R15 — dbuf K/V gload_lds, swapped QK^T, packed P_lds writes
//   gemm2_k:   128x256 BK=64, relaxed 1-barrier/tile, depth-2 counted vmcnt(6)

typedef __attribute__((ext_vector_type(8))) short bf16x8;
typedef __attribute__((ext_vector_type(4))) float f32x4;

#define GLOAD_LDS16(gp, lp)                                                              \
  __builtin_amdgcn_global_load_lds((const __attribute__((address_space(1))) void*)(gp),  \
                                   (__attribute__((address_space(3))) void*)(lp), 16, 0, 0)

__device__ __forceinline__ unsigned short f2bf(float f) {
  unsigned int u = __float_as_uint(f);
  u += 0x7fffu + ((u >> 16) & 1u);          // RNE
  return (unsigned short)(u >> 16);
}

// ---------------------------------------------------------------------------
// Fused pre-pass: blocks [0,2048) cast x->bf16; [2048,5120) transpose W_qkv;
// [5120,6144) transpose W_o.
// ---------------------------------------------------------------------------
__global__ __launch_bounds__(256) void prep_fused(
    const float* __restrict__ x, unsigned short* __restrict__ x_bf,
    const float* __restrict__ W_qkv, unsigned short* __restrict__ wqkv_t,
    const float* __restrict__ W_o, unsigned short* __restrict__ wo_t) {
  const int b = blockIdx.x;
  if (b < 2048) {
    const int n4 = 8388608 / 4;
    for (int i = b * 256 + threadIdx.x; i < n4; i += 2048 * 256) {
      float4 v = reinterpret_cast<const float4*>(x)[i];
      ushort4 o;
      o.x = f2bf(v.x); o.y = f2bf(v.y); o.z = f2bf(v.z); o.w = f2bf(v.w);
      reinterpret_cast<ushort4*>(x_bf)[i] = o;
    }
  } else {
    __shared__ float tile[32][33];
    const float* W;
    unsigned short* Wt;
    int R = 1024, C, bx, by;
    if (b < 5120) {
      W = W_qkv; Wt = wqkv_t; C = 3072;
      int bb = b - 2048; bx = bb % 96; by = bb / 96;
    } else {
      W = W_o; Wt = wo_t; C = 1024;
      int bb = b - 5120; bx = bb & 31; by = bb >> 5;
    }
    const int tx = threadIdx.x & 31, ty = threadIdx.x >> 5;
    const int c0 = bx * 32, r0 = by * 32;
    #pragma unroll
    for (int i = 0; i < 4; i++) {
      int r = r0 + ty + i * 8;
      tile[ty + i * 8][tx] = W[(size_t)r * C + c0 + tx];
    }
    __syncthreads();
    #pragma unroll
    for (int i = 0; i < 4; i++) {
      int c = c0 + ty + i * 8;
      Wt[(size_t)c * R + r0 + tx] = f2bf(tile[tx][ty + i * 8]);
    }
  }
}

// ---------------------------------------------------------------------------
// GEMM1: 128x384, BK=32, 512 thr (8 waves = 2M x 4N; 64x96 per wave, 4x6
// frags). 3-buf LDS (96 KB), stage kt+2 during kt, ONE tile-top vmcnt(4)+
// barrier+sched_barrier per tile. qkv scatter epilogue with per-frag `which`.
// ---------------------------------------------------------------------------
__global__ __launch_bounds__(512) void gemm1_384(
    const unsigned short* __restrict__ A, const unsigned short* __restrict__ Bt,
    const float* __restrict__ bias, unsigned short* __restrict__ qkv_out) {
  __shared__ __align__(16) unsigned short As[3][128 * 32];   // 24 KB
  __shared__ __align__(16) unsigned short Bs[3][384 * 32];   // 72 KB
  const int t = threadIdx.x;
  const int lane = t & 63, wid = t >> 6;
  const int lr = lane & 15, g = lane >> 4;
  const int wm = wid >> 2, wn = wid & 3;

  const int nwg = gridDim.x * gridDim.y;
  const int id = blockIdx.x + gridDim.x * blockIdx.y;
  const int sw = (id & 7) * (nwg >> 3) + (id >> 3);
  const int bx = sw % gridDim.x, by = sw / gridDim.x;
  const int row0 = by * 128, col0 = bx * 384;

  const int srow = t >> 2;                       // 0..127 (64B rows: 32 bf16)
  const int sch  = (t & 3) ^ ((srow >> 1) & 3);  // source pre-swizzle chunk

  auto stA = [&](int buf, int kt) {
    GLOAD_LDS16(A + (size_t)(row0 + srow) * 1024 + kt * 32 + sch * 8,
                (char*)&As[buf][0] + t * 16);
  };
  auto stB = [&](int buf, int kt, int j) {   // j=0..2: rows j*128..j*128+127
    GLOAD_LDS16(Bt + (size_t)(col0 + j * 128 + srow) * 1024 + kt * 32 + sch * 8,
                (char*)&Bs[buf][0] + j * 8192 + t * 16);
  };
  auto rdA = [&](int buf, int m) -> bf16x8 {
    int r = wm * 64 + m * 16 + lr;
    return *(const bf16x8*)((const char*)&As[buf][0] + r * 64 +
                            ((g ^ ((r >> 1) & 3)) * 16));
  };
  auto rdB = [&](int buf, int n) -> bf16x8 {
    int r = wn * 96 + n * 16 + lr;
    return *(const bf16x8*)((const char*)&Bs[buf][0] + r * 64 +
                            ((g ^ ((r >> 1) & 3)) * 16));
  };

  f32x4 acc[4][6] = {};

  stA(0, 0); stB(0, 0, 0); stB(0, 0, 1); stB(0, 0, 2);
  stA(1, 1); stB(1, 1, 0); stB(1, 1, 1); stB(1, 1, 2);

  for (int kt = 0; kt < 32; kt++) {
    const int buf = kt % 3;
    const int bufn = (kt + 2) % 3;
    const bool pf = (kt <= 29);

    if (kt == 31) asm volatile("s_waitcnt vmcnt(0)" ::: "memory");
    else          asm volatile("s_waitcnt vmcnt(4)" ::: "memory");
    __builtin_amdgcn_s_barrier();
    __builtin_amdgcn_sched_barrier(0);   // staging below must not hoist above

    bf16x8 a[4], b[6];
    #pragma unroll
    for (int m = 0; m < 4; m++) a[m] = rdA(buf, m);
    #pragma unroll
    for (int n = 0; n < 6; n++) b[n] = rdB(buf, n);
    if (pf) { stA(bufn, kt + 2); stB(bufn, kt + 2, 0); stB(bufn, kt + 2, 1); stB(bufn, kt + 2, 2); }
    #pragma unroll
    for (int m = 0; m < 4; m++)
      #pragma unroll
      for (int n = 0; n < 6; n++)
        acc[m][n] = __builtin_amdgcn_mfma_f32_16x16x32_bf16(a[m], b[n], acc[m][n], 0, 0, 0);
  }

  #pragma unroll
  for (int m = 0; m < 4; m++) {
    const int row = row0 + wm * 64 + m * 16 + g * 4;
    const int bb = row >> 10, nn = row & 1023;
    #pragma unroll
    for (int n = 0; n < 6; n++) {
      const int col = col0 + wn * 96 + n * 16 + lr;
      const int which = col >> 10;         // frag-uniform (16 | 1024)
      const int cc = col & 1023;
      const int h = cc >> 6, dk = cc & 63;
      const float bv = bias[col];
      if (which == 2) {
        ushort4 w;
        w.x = f2bf(acc[m][n][0] + bv);
        w.y = f2bf(acc[m][n][1] + bv);
        w.z = f2bf(acc[m][n][2] + bv);
        w.w = f2bf(acc[m][n][3] + bv);
        size_t idx = ((size_t)2 << 23) + (((size_t)(bb * 16 + h)) << 16) +
                     (size_t)dk * 1024 + nn;
        *(ushort4*)(qkv_out + idx) = w;
      } else {
        const float sc = (which == 0) ? 0.125f : 1.0f;
        #pragma unroll
        for (int r = 0; r < 4; r++) {
          size_t idx = ((size_t)which << 23) +
                       (((size_t)((bb * 16 + h) * 1024 + nn + r)) << 6) + dk;
          qkv_out[idx] = f2bf((acc[m][n][r] + bv) * sc);
        }
      }
    }
  }
}

// ---------------------------------------------------------------------------
// GEMM2 (relaxed): 128x256, BK=64, 8 waves (2M x 4N, 64x64/wave), 3-buf,
// stage kt+2, tile-top vmcnt(6)+barrier+sched_barrier. f32 out + bias.
// ---------------------------------------------------------------------------
__global__ __launch_bounds__(512) void gemm2_k(
    const unsigned short* __restrict__ A, const unsigned short* __restrict__ Bt,
    const float* __restrict__ bias, float* __restrict__ Cout) {
  __shared__ __align__(16) unsigned short As[3][128 * 64];   // 48 KB
  __shared__ __align__(16) unsigned short Bs[3][256 * 64];   // 96 KB
  const int t = threadIdx.x;
  const int lane = t & 63, wid = t >> 6;
  const int lr = lane & 15, g = lane >> 4;
  const int wm = wid >> 2, wn = wid & 3;

  const int nwg = gridDim.x * gridDim.y;
  const int id = blockIdx.x + gridDim.x * blockIdx.y;
  const int sw = (id & 7) * (nwg >> 3) + (id >> 3);
  const int bx = sw % gridDim.x, by = sw / gridDim.x;
  const int row0 = by * 128, col0 = bx * 256;

  const int srow = t >> 3, sch = t & 7;     // 64 rows of 128B

  auto stA = [&](int buf, int kt, int j) {  // j=0..1
    int row = j * 64 + srow;
    int ch = sch ^ (row & 7);
    GLOAD_LDS16(A + (size_t)(row0 + row) * 1024 + kt * 64 + ch * 8,
                (char*)&As[buf][0] + j * 8192 + t * 16);
  };
  auto stB = [&](int buf, int kt, int j) {  // j=0..3
    int row = j * 64 + srow;
    int ch = sch ^ (row & 7);
    GLOAD_LDS16(Bt + (size_t)(col0 + row) * 1024 + kt * 64 + ch * 8,
                (char*)&Bs[buf][0] + j * 8192 + t * 16);
  };
  auto rdA = [&](int buf, int c, int m) -> bf16x8 {
    int r = wm * 64 + m * 16 + lr;
    return *(const bf16x8*)((const char*)&As[buf][0] + r * 128 +
                            ((c * 64 + g * 16) ^ ((r & 7) << 4)));
  };
  auto rdB = [&](int buf, int c, int n) -> bf16x8 {
    int r = wn * 64 + n * 16 + lr;
    return *(const bf16x8*)((const char*)&Bs[buf][0] + r * 128 +
                            ((c * 64 + g * 16) ^ ((r & 7) << 4)));
  };

  f32x4 acc[4][4] = {};

  stA(0, 0, 0); stA(0, 0, 1);
  stB(0, 0, 0); stB(0, 0, 1); stB(0, 0, 2); stB(0, 0, 3);
  stA(1, 1, 0); stA(1, 1, 1);
  stB(1, 1, 0); stB(1, 1, 1); stB(1, 1, 2); stB(1, 1, 3);

  for (int kt = 0; kt < 16; kt++) {
    const int buf = kt % 3;
    const int bufn = (kt + 2) % 3;
    const bool pf = (kt <= 13);

    if (kt == 15) asm volatile("s_waitcnt vmcnt(0)" ::: "memory");
    else          asm volatile("s_waitcnt vmcnt(6)" ::: "memory");
    __builtin_amdgcn_s_barrier();
    __builtin_amdgcn_sched_barrier(0);

    bf16x8 a0[4], b0[4];
    #pragma unroll
    for (int m = 0; m < 4; m++) a0[m] = rdA(buf, 0, m);
    #pragma unroll
    for (int n = 0; n < 4; n++) b0[n] = rdB(buf, 0, n);
    if (pf) { stA(bufn, kt + 2, 0); stA(bufn, kt + 2, 1); stB(bufn, kt + 2, 0); }
    #pragma unroll
    for (int m = 0; m < 4; m++)
      #pragma unroll
      for (int n = 0; n < 4; n++)
        acc[m][n] = __builtin_amdgcn_mfma_f32_16x16x32_bf16(a0[m], b0[n], acc[m][n], 0, 0, 0);

    bf16x8 a1[4], b1[4];
    #pragma unroll
    for (int m = 0; m < 4; m++) a1[m] = rdA(buf, 1, m);
    #pragma unroll
    for (int n = 0; n < 4; n++) b1[n] = rdB(buf, 1, n);
    if (pf) { stB(bufn, kt + 2, 1); stB(bufn, kt + 2, 2); stB(bufn, kt + 2, 3); }
    #pragma unroll
    for (int m = 0; m < 4; m++)
      #pragma unroll
      for (int n = 0; n < 4; n++)
        acc[m][n] = __builtin_amdgcn_mfma_f32_16x16x32_bf16(a1[m], b1[n], acc[m][n], 0, 0, 0);
  }

  #pragma unroll
  for (int m = 0; m < 4; m++) {
    #pragma unroll
    for (int n = 0; n < 4; n++) {
      int col = col0 + wn * 64 + n * 16 + lr;
      #pragma unroll
      for (int r = 0; r < 4; r++) {
        int row = row0 + wm * 64 + m * 16 + g * 4 + r;
        Cout[(size_t)row * 1024 + col] = acc[m][n][r] + bias[col];
      }
    }
  }
}

// ---------------------------------------------------------------------------
// Attention (R15 proven): 8 waves, QBLK=128, KVBLK=64, dbuf K+V via swizzled
// global_load_lds. Swapped QK^T (s4 = mfma(K,Q)): lane holds P[q=lr][4
// consecutive k] -> packed ds_write_b64; den scalar per lane, reduced at end.
// ---------------------------------------------------------------------------
__global__ __launch_bounds__(512) void attn_mfma(
    const unsigned short* __restrict__ qkv, unsigned short* __restrict__ attn_out) {
  __shared__ __align__(16) unsigned short K_lds[2][64 * 64];   // [k][d] swz
  __shared__ __align__(16) unsigned short V_lds[2][64 * 64];   // [d][k] swz
  __shared__ __align__(16) unsigned short P_lds[128 * 64];     // [q][k] swz

  const int bid = ((blockIdx.x & 7) << 7) + (blockIdx.x >> 3);
  const int bh = bid >> 3, qt = bid & 7;
  const unsigned short* Qp = qkv + ((size_t)bh << 16);
  const unsigned short* Kp = qkv + (1u << 23) + ((size_t)bh << 16);
  const unsigned short* Vt = qkv + (2u << 23) + ((size_t)bh << 16);  // [dk][n]

  const int t = threadIdx.x;
  const int lane = t & 63, wid = t >> 6;
  const int lr = lane & 15, g = lane >> 4;

  bf16x8 qf[2];
  {
    int qrow = qt * 128 + wid * 16 + lr;
    qf[0] = *(const bf16x8*)(Qp + (size_t)qrow * 64 + g * 8);
    qf[1] = *(const bf16x8*)(Qp + (size_t)qrow * 64 + 32 + g * 8);
  }

  const int srow = t >> 3;
  const int sch  = (t & 7) ^ (srow & 7);
  const int so   = t * 16;

  auto stage = [&](int buf, int kt) {
    GLOAD_LDS16(Kp + (size_t)(kt * 64 + srow) * 64 + sch * 8, (char*)&K_lds[buf][0] + so);
    GLOAD_LDS16(Vt + (size_t)srow * 1024 + kt * 64 + sch * 8, (char*)&V_lds[buf][0] + so);
  };

  f32x4 o_acc[4] = {};
  float den_l = 0.f;
  const int qrow_w = wid * 16 + lr;

  stage(0, 0);
  __syncthreads();
  int buf = 0;
  for (int kt = 0; kt < 16; kt++) {
    if (kt + 1 < 16) stage(buf ^ 1, kt + 1);

    f32x4 s4[4] = {};
    __builtin_amdgcn_s_setprio(1);
    #pragma unroll
    for (int ks = 0; ks < 4; ks++) {
      int krow = ks * 16 + lr;
      #pragma unroll
      for (int c = 0; c < 2; c++) {
        bf16x8 kf = *(const bf16x8*)((char*)&K_lds[buf][0] + krow * 128 +
                                     ((c * 64 + g * 16) ^ ((krow & 7) << 4)));
        s4[ks] = __builtin_amdgcn_mfma_f32_16x16x32_bf16(kf, qf[c], s4[ks], 0, 0, 0);
      }
    }
    __builtin_amdgcn_s_setprio(0);

    #pragma unroll
    for (int ks = 0; ks < 4; ks++) {
      float e0 = __expf(s4[ks][0]);
      float e1 = __expf(s4[ks][1]);
      float e2 = __expf(s4[ks][2]);
      float e3 = __expf(s4[ks][3]);
      den_l += (e0 + e1) + (e2 + e3);
      unsigned int lo = (unsigned int)f2bf(e0) | ((unsigned int)f2bf(e1) << 16);
      unsigned int hi = (unsigned int)f2bf(e2) | ((unsigned int)f2bf(e3) << 16);
      int k0 = ks * 16 + g * 4;
      *(uint2*)((char*)P_lds + qrow_w * 128 +
                ((k0 * 2) ^ ((qrow_w & 7) << 4))) = make_uint2(lo, hi);
    }

    bf16x8 pa[2];
    {
      int q = wid * 16 + lr;
      #pragma unroll
      for (int c = 0; c < 2; c++)
        pa[c] = *(const bf16x8*)((char*)P_lds + q * 128 +
                                 ((c * 64 + g * 16) ^ ((q & 7) << 4)));
    }
    __builtin_amdgcn_s_setprio(1);
    #pragma unroll
    for (int ds_ = 0; ds_ < 4; ds_++) {
      int drow = ds_ * 16 + lr;
      #pragma unroll
      for (int c = 0; c < 2; c++) {
        bf16x8 vf = *(const bf16x8*)((char*)&V_lds[buf][0] + drow * 128 +
                                     ((c * 64 + g * 16) ^ ((drow & 7) << 4)));
        o_acc[ds_] = __builtin_amdgcn_mfma_f32_16x16x32_bf16(pa[c], vf, o_acc[ds_], 0, 0, 0);
      }
    }
    __builtin_amdgcn_s_setprio(0);
    __syncthreads();
    buf ^= 1;
  }

  den_l += __shfl_xor(den_l, 16, 64);
  den_l += __shfl_xor(den_l, 32, 64);
  float den_r[4];
  #pragma unroll
  for (int r = 0; r < 4; r++) den_r[r] = __shfl(den_l, g * 4 + r, 64);

  const int bb = bh >> 4, h = bh & 15;
  #pragma unroll
  for (int ds_ = 0; ds_ < 4; ds_++) {
    #pragma unroll
    for (int r = 0; r < 4; r++) {
      int q = qt * 128 + wid * 16 + g * 4 + r;
      int d = h * 64 + ds_ * 16 + lr;
      attn_out[((size_t)(bb * 1024 + q)) * 1024 + d] = f2bf(o_acc[ds_][r] / den_r[r]);
    }
  }
}

// ---------------------------------------------------------------------------
extern "C" void kernel_launch(void* const* d_in, const int* in_sizes, int n_in,
                              void* d_out, int out_size, void* d_ws, size_t ws_size,
                              hipStream_t stream) {
  const float* x     = (const float*)d_in[0];
  const float* W_qkv = (const float*)d_in[1];
  const float* b_qkv = (const float*)d_in[2];
  const float* W_o   = (const float*)d_in[3];
  const float* b_o   = (const float*)d_in[4];
  float* out = (float*)d_out;

  unsigned short* ws      = (unsigned short*)d_ws;
  unsigned short* x_bf    = ws;                     //  8388608
  unsigned short* wqkv_t  = x_bf + 8388608;         //  3145728
  unsigned short* wo_t    = wqkv_t + 3145728;       //  1048576
  unsigned short* qkv     = wo_t + 1048576;         // 25165824 (3 x 2^23)
  unsigned short* attn_o  = qkv + 25165824;         //  8388608

  prep_fused<<<6144, 256, 0, stream>>>(x, x_bf, W_qkv, wqkv_t, W_o, wo_t);
  // GEMM1: 8192x3072, 128x384 tiles -> grid 8x64 = 512 blocks (2 exact rounds)
  gemm1_384<<<dim3(8, 64), 512, 0, stream>>>(x_bf, wqkv_t, b_qkv, qkv);
  attn_mfma<<<1024, 512, 0, stream>>>(qkv, attn_o);
  // GEMM2: 8192x1024, 128x256 tiles -> grid 4x64 = 256 blocks (1 exact round)
  gemm2_k<<<dim3(4, 64), 512, 0, stream>>>(attn_o, wo_t, b_o, out);
}